// Round 19
// baseline (134.003 us; speedup 1.0000x reference)
//
#include <hip/hip_runtime.h>
#include <hip/hip_bf16.h>

typedef __attribute__((ext_vector_type(4))) float f32x4;
typedef __attribute__((ext_vector_type(8))) short s16x8;
typedef __attribute__((ext_vector_type(4))) short s16x4;

#define DEV __device__ __forceinline__

DEV unsigned short f2bf(float f) {
  union { float f; unsigned u; } v; v.f = f;
  unsigned r = v.u + 0x7FFFu + ((v.u >> 16) & 1u);
  return (unsigned short)(r >> 16);
}

DEV s16x4 cvt4(const f32x4 a) {
  unsigned u0, u1;
  asm("v_cvt_pk_bf16_f32 %0, %1, %2" : "=v"(u0) : "v"(a[0]), "v"(a[1]));
  asm("v_cvt_pk_bf16_f32 %0, %1, %2" : "=v"(u1) : "v"(a[2]), "v"(a[3]));
  union { s16x4 v; unsigned uu[2]; } r;
  r.uu[0] = u0; r.uu[1] = u1;
  return r.v;
}

DEV float bf2f(unsigned short h) {
  union { unsigned u; float f; } v;
  v.u = ((unsigned)h) << 16;
  return v.f;
}

// ---------------- fused QKV projection (R17 exact — best measured) ----------------
// out_mode 1 (V): writes V^T[n][d][t'] with t' rho-permuted within each 32-key
// block: ks(t) = ((t>>2)&3)*8 + ((t>>4)&1)*4 + (t&3). Permutation spans 64B.
__global__ __launch_bounds__(256) void proj_kernel(
    const float* __restrict__ Qx, const float* __restrict__ Kx, const float* __restrict__ Vx,
    const float* __restrict__ Wq, const float* __restrict__ bq,
    const float* __restrict__ Wk, const float* __restrict__ bk,
    const float* __restrict__ Wv, const float* __restrict__ bv,
    unsigned short* __restrict__ qb, unsigned short* __restrict__ kb,
    unsigned short* __restrict__ vt)
{
  const int z = blockIdx.z;
  const float* X = (z == 0) ? Qx : (z == 1) ? Kx : Vx;
  const float* W = (z == 0) ? Wq : (z == 1) ? Wk : Wv;
  const float* B = (z == 0) ? bq : (z == 1) ? bk : bv;
  unsigned short* Y = (z == 0) ? qb : (z == 1) ? kb : vt;
  const int out_mode = (z == 2);

  const int row0 = blockIdx.x * 128;
  const int col0 = blockIdx.y * 128;
  const int tid  = threadIdx.x;
  const int lane = tid & 63;
  const int w    = tid >> 6;
  const int wr = w >> 1, wc = w & 1;
  const int l15 = lane & 15, lg = lane >> 4;

  __shared__ unsigned short As[128][40];
  __shared__ unsigned short Bs[128][40];

  f32x4 acc[4][4];
  #pragma unroll
  for (int i = 0; i < 4; ++i)
    #pragma unroll
    for (int j = 0; j < 4; ++j) acc[i][j] = {0.f, 0.f, 0.f, 0.f};

  const int lr = tid >> 3;
  const int lc = (tid & 7) << 2;

  for (int k0 = 0; k0 < 256; k0 += 32) {
    __syncthreads();
    #pragma unroll
    for (int p = 0; p < 4; ++p) {
      const int r = p * 32 + lr;
      f32x4 a = *reinterpret_cast<const f32x4*>(&X[(size_t)(row0 + r) * 256 + k0 + lc]);
      *reinterpret_cast<s16x4*>(&As[r][lc]) = cvt4(a);
      f32x4 b = *reinterpret_cast<const f32x4*>(&W[(size_t)(col0 + r) * 256 + k0 + lc]);
      *reinterpret_cast<s16x4*>(&Bs[r][lc]) = cvt4(b);
    }
    __syncthreads();
    s16x8 af[4], bf[4];
    #pragma unroll
    for (int mi = 0; mi < 4; ++mi)
      af[mi] = *reinterpret_cast<const s16x8*>(&As[wr * 64 + mi * 16 + l15][lg * 8]);
    #pragma unroll
    for (int ni = 0; ni < 4; ++ni)
      bf[ni] = *reinterpret_cast<const s16x8*>(&Bs[wc * 64 + ni * 16 + l15][lg * 8]);
    #pragma unroll
    for (int mi = 0; mi < 4; ++mi)
      #pragma unroll
      for (int ni = 0; ni < 4; ++ni)
        acc[mi][ni] = __builtin_amdgcn_mfma_f32_16x16x32_bf16(af[mi], bf[ni], acc[mi][ni], 0, 0, 0);
  }

  #pragma unroll
  for (int ni = 0; ni < 4; ++ni) {
    const int col = col0 + wc * 64 + ni * 16 + l15;
    const float bv_ = B[col];
    #pragma unroll
    for (int mi = 0; mi < 4; ++mi)
      #pragma unroll
      for (int j = 0; j < 4; ++j) {
        const int row = row0 + wr * 64 + mi * 16 + lg * 4 + j;
        const unsigned short h = f2bf(acc[mi][ni][j] + bv_);
        if (out_mode == 0) {
          Y[(size_t)row * 256 + col] = h;
        } else {
          const int t  = row & 4095;
          const int tp = (t & ~31) | (((t >> 2) & 3) * 8 + ((t >> 4) & 1) * 4 + (t & 3));
          Y[((size_t)((row >> 12) * 256 + col)) * 4096 + tp] = h;
        }
      }
  }
}

// ---------------- flash attention: 48KB LDS (K dbuf + V single), bf16 partials --------------
// 256 thr = 4 waves x 32q (q-span 128). K double-buffered (2x16KB), V single
// (16KB, staged per-iter after the B1 read-retire barrier). Counted vmcnt(4)
// steady state (drains K(i)+V(i); K(i+1) in flight). 3 blocks resident/CU.
// Swapped QK^T, static-max softmax, in-register P pack, ones-MFMA row-sum.
// Keys split across blocks (TS, up to 8); bf16 unnormalized partials to ws.
__global__ __launch_bounds__(256, 2) void attn_kernel(
    const unsigned short* __restrict__ Qb,
    const unsigned short* __restrict__ Kb,
    const unsigned short* __restrict__ Vt,
    unsigned short* __restrict__ pO, float* __restrict__ pML, const int TS)
{
  // K tile [32key][256d] 16KB x2; granule slot g holds global granule g^(key&7)
  // V tile [256d][32ks]  16KB x1; granule slot g holds global granule g^((d>>1)&3)
  __shared__ __align__(16) unsigned short smem[24576];   // 32KB K + 16KB V = 48KB

  const int o   = blockIdx.x;
  const int cpx = gridDim.x >> 3;
  const int wg  = (o & 7) * cpx + (o >> 3);   // bijective XCD swizzle (grid % 8 == 0)
  const int qtile = wg & 127;
  const int ts    = wg >> 7;
  const int n  = qtile >> 5;
  const int q0 = (qtile & 31) * 128;

  const int tid  = threadIdx.x;
  const int lane = tid & 63;
  const int w    = tid >> 6;   // 0..3 : q-group (32 q each)
  const int l15  = lane & 15;
  const int lg   = lane >> 4;

  const int range = 4096 / TS;
  const int NT    = range >> 5;
  const int tbase = ts * range;

  const unsigned short* kbase = Kb + ((size_t)n * 4096) * 256;
  const unsigned short* vbase = Vt + ((size_t)n * 256) * 4096;

  // per-lane staging offsets (elements)
  unsigned kOff[4], vOff[4];
  #pragma unroll
  for (int ld = 0; ld < 4; ++ld) {
    const int gi  = ld * 256 + w * 64 + lane;        // 16B units
    const int key = gi >> 5, slot = gi & 31;
    kOff[ld] = (unsigned)(key * 256 + (slot ^ (key & 7)) * 8);
    const int d = gi >> 2, gv = gi & 3;
    vOff[ld] = (unsigned)(d * 4096 + ((gv ^ ((d >> 1) & 3)) * 8));
  }

  #define STAGE_K(BUF, T0)                                                            \
    do {                                                                              \
      unsigned short* kd = &smem[(BUF) * 8192];                                       \
      _Pragma("unroll")                                                               \
      for (int ld = 0; ld < 4; ++ld)                                                  \
        __builtin_amdgcn_global_load_lds(                                             \
            (const __attribute__((address_space(1))) unsigned int*)                   \
                (kbase + (size_t)(T0) * 256 + kOff[ld]),                              \
            (__attribute__((address_space(3))) unsigned int*)                         \
                &kd[(ld * 256 + w * 64 + lane) * 8], 16, 0, 0);                       \
    } while (0)

  #define STAGE_V(T0)                                                                 \
    do {                                                                              \
      unsigned short* vd = &smem[16384];                                              \
      _Pragma("unroll")                                                               \
      for (int ld = 0; ld < 4; ++ld)                                                  \
        __builtin_amdgcn_global_load_lds(                                             \
            (const __attribute__((address_space(1))) unsigned int*)                   \
                (vbase + (size_t)(T0) + vOff[ld]),                                    \
            (__attribute__((address_space(3))) unsigned int*)                         \
                &vd[(ld * 256 + w * 64 + lane) * 8], 16, 0, 0);                       \
    } while (0)

  // Q fragments (B-operand: col=q=l15): 32 q-rows/wave
  s16x8 aq[2][8];
  #pragma unroll
  for (int qk = 0; qk < 2; ++qk) {
    const size_t qoff = ((size_t)(n * 4096 + q0 + w * 32 + qk * 16 + l15)) * 256 + lg * 8;
    #pragma unroll
    for (int kg = 0; kg < 8; ++kg)
      aq[qk][kg] = *reinterpret_cast<const s16x8*>(&Qb[qoff + kg * 32]);
  }
  __builtin_amdgcn_sched_barrier(0);
  asm volatile("s_waitcnt vmcnt(0)" ::: "memory");   // clean queue before counted pipeline
  __builtin_amdgcn_sched_barrier(0);

  f32x4 o_acc[2][16];   // O[q=qk*16+l15][d = dt*16 + lg*4 + j]
  #pragma unroll
  for (int qk = 0; qk < 2; ++qk)
    #pragma unroll
    for (int dt = 0; dt < 16; ++dt) o_acc[qk][dt] = {0.f, 0.f, 0.f, 0.f};
  f32x4 l_acc[2];
  l_acc[0] = {0.f, 0.f, 0.f, 0.f};
  l_acc[1] = {0.f, 0.f, 0.f, 0.f};

  s16x8 ones;
  #pragma unroll
  for (int i = 0; i < 8; ++i) ones[i] = (short)0x3F80;   // bf16 1.0

  const float c  = 0.09016844005f;    // (1/sqrt(256)) * log2(e)
  const float b0 = -8.656170245f;     // -96 * c  (static max 96)

  STAGE_K(0, tbase);   // prologue: K(0) in flight (4 loads/wave)

  for (int i = 0; i < NT; ++i) {
    // B1: all waves' LDS reads of V(i-1) and Kbuf[(i+1)&1] (=QK(i-1)'s buf) retired.
    __builtin_amdgcn_sched_barrier(0);
    asm volatile("s_waitcnt lgkmcnt(0)" ::: "memory");
    __builtin_amdgcn_sched_barrier(0);
    __builtin_amdgcn_s_barrier();                        // B1
    __builtin_amdgcn_sched_barrier(0);

    STAGE_V(tbase + i * 32);                             // V(i) -> single buffer
    if (i + 1 < NT) {
      STAGE_K((i + 1) & 1, tbase + (i + 1) * 32);        // K(i+1) -> other K buf
      asm volatile("s_waitcnt vmcnt(4)" ::: "memory");   // K(i)+V(i) landed; K(i+1) flies
    } else {
      asm volatile("s_waitcnt vmcnt(0)" ::: "memory");
    }
    __builtin_amdgcn_sched_barrier(0);
    __builtin_amdgcn_s_barrier();                        // B2: tile i visible to all
    __builtin_amdgcn_sched_barrier(0);

    const unsigned short* Kt = &smem[(i & 1) * 8192];
    const unsigned short* Vw = &smem[16384];

    // swapped QK^T: S^T[key][q] = mfma(A=K, B=Q)
    f32x4 s[2][2];
    #pragma unroll
    for (int qk = 0; qk < 2; ++qk) { s[qk][0] = {0.f,0.f,0.f,0.f}; s[qk][1] = {0.f,0.f,0.f,0.f}; }
    __builtin_amdgcn_s_setprio(1);
    #pragma unroll
    for (int nt = 0; nt < 2; ++nt) {
      const int key = nt * 16 + l15;
      #pragma unroll
      for (int kg = 0; kg < 8; ++kg) {
        const s16x8 kf = *reinterpret_cast<const s16x8*>(
            &Kt[key * 256 + (((kg * 4 + lg) ^ (l15 & 7)) * 8)]);
        s[0][nt] = __builtin_amdgcn_mfma_f32_16x16x32_bf16(kf, aq[0][kg], s[0][nt], 0, 0, 0);
        s[1][nt] = __builtin_amdgcn_mfma_f32_16x16x32_bf16(kf, aq[1][kg], s[1][nt], 0, 0, 0);
      }
    }
    __builtin_amdgcn_s_setprio(0);

    // static-max softmax + pack to PV B-frag, all in-register.
    s16x8 pb[2];
    #pragma unroll
    for (int qk = 0; qk < 2; ++qk) {
      unsigned u[4];
      #pragma unroll
      for (int h = 0; h < 4; ++h) {
        const int nt = h >> 1, j0 = (h & 1) * 2;
        const float p0 = exp2f(fmaf(s[qk][nt][j0],     c, b0));
        const float p1 = exp2f(fmaf(s[qk][nt][j0 + 1], c, b0));
        asm("v_cvt_pk_bf16_f32 %0, %1, %2" : "=v"(u[h]) : "v"(p0), "v"(p1));
      }
      union { s16x8 v; unsigned uu[4]; } cvt;
      cvt.uu[0] = u[0]; cvt.uu[1] = u[1]; cvt.uu[2] = u[2]; cvt.uu[3] = u[3];
      pb[qk] = cvt.v;
    }

    // PV: O accum. A = V-frag (row=d, k=ks), B = pb (col=q, k=ks).
    __builtin_amdgcn_s_setprio(1);
    l_acc[0] = __builtin_amdgcn_mfma_f32_16x16x32_bf16(ones, pb[0], l_acc[0], 0, 0, 0);
    l_acc[1] = __builtin_amdgcn_mfma_f32_16x16x32_bf16(ones, pb[1], l_acc[1], 0, 0, 0);
    #pragma unroll
    for (int dt = 0; dt < 16; ++dt) {
      const int d = dt * 16 + l15;
      const s16x8 vf = *reinterpret_cast<const s16x8*>(
          &Vw[d * 32 + ((lg ^ ((d >> 1) & 3)) * 8)]);
      o_acc[0][dt] = __builtin_amdgcn_mfma_f32_16x16x32_bf16(vf, pb[0], o_acc[0][dt], 0, 0, 0);
      o_acc[1][dt] = __builtin_amdgcn_mfma_f32_16x16x32_bf16(vf, pb[1], o_acc[1][dt], 0, 0, 0);
    }
    __builtin_amdgcn_s_setprio(0);
  }

  // epilogue: bf16 partials (8B stores); l from ones-MFMA (rows identical)
  #pragma unroll
  for (int qk = 0; qk < 2; ++qk) {
    const size_t r = (size_t)ts * 16384 + n * 4096 + q0 + w * 32 + qk * 16 + l15;
    if (lg == 0) pML[r] = l_acc[qk][0];
    #pragma unroll
    for (int dt = 0; dt < 16; ++dt)
      *reinterpret_cast<s16x4*>(&pO[r * 256 + dt * 16 + lg * 4]) = cvt4(o_acc[qk][dt]);
  }
  #undef STAGE_K
  #undef STAGE_V
}

// ---------------- cross-block T-split merge (bf16 partials, plain sums) ----------------
__global__ __launch_bounds__(256) void merge_kernel(
    const unsigned short* __restrict__ pO, const float* __restrict__ pML,
    float* __restrict__ out, const int TS)
{
  const int idx = blockIdx.x * 256 + threadIdx.x;
  const int row = idx >> 6;
  const int dp  = (idx & 63) << 2;

  f32x4 num = {0.f, 0.f, 0.f, 0.f};
  float den = 0.f;
  for (int t = 0; t < TS; ++t) {
    den += pML[(size_t)t * 16384 + row];
    const s16x4 o = *reinterpret_cast<const s16x4*>(&pO[((size_t)t * 16384 + row) * 256 + dp]);
    num[0] += bf2f((unsigned short)o[0]);
    num[1] += bf2f((unsigned short)o[1]);
    num[2] += bf2f((unsigned short)o[2]);
    num[3] += bf2f((unsigned short)o[3]);
  }
  const float inv = 1.0f / den;
  f32x4 y = { num[0] * inv, num[1] * inv, num[2] * inv, num[3] * inv };
  *reinterpret_cast<f32x4*>(&out[(size_t)row * 256 + dp]) = y;
}

extern "C" void kernel_launch(void* const* d_in, const int* in_sizes, int n_in,
                              void* d_out, int out_size, void* d_ws, size_t ws_size,
                              hipStream_t stream) {
  const float* query = (const float*)d_in[0];
  const float* key   = (const float*)d_in[1];
  const float* value = (const float*)d_in[2];
  const float* Wq    = (const float*)d_in[3];
  const float* bq    = (const float*)d_in[4];
  const float* Wk    = (const float*)d_in[5];
  const float* bk    = (const float*)d_in[6];
  const float* Wv    = (const float*)d_in[7];
  const float* bv    = (const float*)d_in[8];
  float* out = (float*)d_out;

  unsigned short* qb = (unsigned short*)d_ws;              // [16384][256] bf16
  unsigned short* kb = qb + (size_t)16384 * 256;           // [16384][256] bf16
  unsigned short* vt = kb + (size_t)16384 * 256;           // [4][256][4096] bf16 (rho-permuted)
  const size_t base    = (size_t)3 * 16384 * 256 * 2;      // 24 MB
  const size_t poBytes = (size_t)16384 * 256 * 2;          // 8 MB per ts (bf16)
  const size_t mlBytes = (size_t)16384 * 4;                // 64 KB per ts
  const int TS = (ws_size >= base + 8 * (poBytes + mlBytes)) ? 8
               : (ws_size >= base + 4 * (poBytes + mlBytes)) ? 4 : 2;
  unsigned short* pO = (unsigned short*)((char*)d_ws + base);
  float* pML = (float*)((char*)d_ws + base + (size_t)TS * poBytes);
  (void)in_sizes; (void)n_in; (void)out_size;

  proj_kernel<<<dim3(128, 2, 3), 256, 0, stream>>>(query, key, value,
                                                   Wq, bq, Wk, bk, Wv, bv,
                                                   qb, kb, vt);
  attn_kernel<<<dim3(128 * TS), 256, 0, stream>>>(qb, kb, vt, pO, pML, TS);
  merge_kernel<<<dim3(4096), 256, 0, stream>>>(pO, pML, out, TS);
}

// Round 20
// 117.158 us; speedup vs baseline: 1.1438x; 1.1438x over previous
//
#include <hip/hip_runtime.h>
#include <hip/hip_bf16.h>

typedef __attribute__((ext_vector_type(4))) float f32x4;
typedef __attribute__((ext_vector_type(8))) short s16x8;
typedef __attribute__((ext_vector_type(4))) short s16x4;

#define DEV __device__ __forceinline__

DEV unsigned short f2bf(float f) {
  union { float f; unsigned u; } v; v.f = f;
  unsigned r = v.u + 0x7FFFu + ((v.u >> 16) & 1u);
  return (unsigned short)(r >> 16);
}

DEV s16x4 cvt4(const f32x4 a) {
  unsigned u0, u1;
  asm("v_cvt_pk_bf16_f32 %0, %1, %2" : "=v"(u0) : "v"(a[0]), "v"(a[1]));
  asm("v_cvt_pk_bf16_f32 %0, %1, %2" : "=v"(u1) : "v"(a[2]), "v"(a[3]));
  union { s16x4 v; unsigned uu[2]; } r;
  r.uu[0] = u0; r.uu[1] = u1;
  return r.v;
}

DEV float bf2f(unsigned short h) {
  union { unsigned u; float f; } v;
  v.u = ((unsigned)h) << 16;
  return v.f;
}

// ---------------- fused QKV projection (R17 exact — best measured) ----------------
// out_mode 1 (V): writes V^T[n][d][t'] with t' rho-permuted within each 32-key
// block: ks(t) = ((t>>2)&3)*8 + ((t>>4)&1)*4 + (t&3). Permutation spans 64B.
__global__ __launch_bounds__(256) void proj_kernel(
    const float* __restrict__ Qx, const float* __restrict__ Kx, const float* __restrict__ Vx,
    const float* __restrict__ Wq, const float* __restrict__ bq,
    const float* __restrict__ Wk, const float* __restrict__ bk,
    const float* __restrict__ Wv, const float* __restrict__ bv,
    unsigned short* __restrict__ qb, unsigned short* __restrict__ kb,
    unsigned short* __restrict__ vt)
{
  const int z = blockIdx.z;
  const float* X = (z == 0) ? Qx : (z == 1) ? Kx : Vx;
  const float* W = (z == 0) ? Wq : (z == 1) ? Wk : Wv;
  const float* B = (z == 0) ? bq : (z == 1) ? bk : bv;
  unsigned short* Y = (z == 0) ? qb : (z == 1) ? kb : vt;
  const int out_mode = (z == 2);

  const int row0 = blockIdx.x * 128;
  const int col0 = blockIdx.y * 128;
  const int tid  = threadIdx.x;
  const int lane = tid & 63;
  const int w    = tid >> 6;
  const int wr = w >> 1, wc = w & 1;
  const int l15 = lane & 15, lg = lane >> 4;

  __shared__ unsigned short As[128][40];
  __shared__ unsigned short Bs[128][40];

  f32x4 acc[4][4];
  #pragma unroll
  for (int i = 0; i < 4; ++i)
    #pragma unroll
    for (int j = 0; j < 4; ++j) acc[i][j] = {0.f, 0.f, 0.f, 0.f};

  const int lr = tid >> 3;
  const int lc = (tid & 7) << 2;

  for (int k0 = 0; k0 < 256; k0 += 32) {
    __syncthreads();
    #pragma unroll
    for (int p = 0; p < 4; ++p) {
      const int r = p * 32 + lr;
      f32x4 a = *reinterpret_cast<const f32x4*>(&X[(size_t)(row0 + r) * 256 + k0 + lc]);
      *reinterpret_cast<s16x4*>(&As[r][lc]) = cvt4(a);
      f32x4 b = *reinterpret_cast<const f32x4*>(&W[(size_t)(col0 + r) * 256 + k0 + lc]);
      *reinterpret_cast<s16x4*>(&Bs[r][lc]) = cvt4(b);
    }
    __syncthreads();
    s16x8 af[4], bf[4];
    #pragma unroll
    for (int mi = 0; mi < 4; ++mi)
      af[mi] = *reinterpret_cast<const s16x8*>(&As[wr * 64 + mi * 16 + l15][lg * 8]);
    #pragma unroll
    for (int ni = 0; ni < 4; ++ni)
      bf[ni] = *reinterpret_cast<const s16x8*>(&Bs[wc * 64 + ni * 16 + l15][lg * 8]);
    #pragma unroll
    for (int mi = 0; mi < 4; ++mi)
      #pragma unroll
      for (int ni = 0; ni < 4; ++ni)
        acc[mi][ni] = __builtin_amdgcn_mfma_f32_16x16x32_bf16(af[mi], bf[ni], acc[mi][ni], 0, 0, 0);
  }

  #pragma unroll
  for (int ni = 0; ni < 4; ++ni) {
    const int col = col0 + wc * 64 + ni * 16 + l15;
    const float bv_ = B[col];
    #pragma unroll
    for (int mi = 0; mi < 4; ++mi)
      #pragma unroll
      for (int j = 0; j < 4; ++j) {
        const int row = row0 + wr * 64 + mi * 16 + lg * 4 + j;
        const unsigned short h = f2bf(acc[mi][ni][j] + bv_);
        if (out_mode == 0) {
          Y[(size_t)row * 256 + col] = h;
        } else {
          const int t  = row & 4095;
          const int tp = (t & ~31) | (((t >> 2) & 3) * 8 + ((t >> 4) & 1) * 4 + (t & 3));
          Y[((size_t)((row >> 12) * 256 + col)) * 4096 + tp] = h;
        }
      }
  }
}

// ---------------- flash attention, swapped-QK in-register P (R12 structure, verified) -------
// 256 thr = 4 waves x 32q (q-span 128). One shared 32-key K/V tile, dbuf,
// 2 barriers/iter, counted vmcnt(8). S^T = mfma(K,Q) -> P lane-local;
// static-max softmax; in-register P pack; ones-MFMA row-sum.
// Keys split across blocks (TS=4); bf16 unnormalized partials to ws.
__global__ __launch_bounds__(256, 2) void attn_kernel(
    const unsigned short* __restrict__ Qb,
    const unsigned short* __restrict__ Kb,
    const unsigned short* __restrict__ Vt,
    unsigned short* __restrict__ pO, float* __restrict__ pML, const int TS)
{
  // K tile [32key][256d] 16KB x2; granule slot g holds global granule g^(key&7)
  // V tile [256d][32ks]  16KB x2; granule slot g holds global granule g^((d>>1)&3)
  __shared__ __align__(16) unsigned short smem[32768];   // 32K K + 32K V = 64KB

  const int o   = blockIdx.x;
  const int cpx = gridDim.x >> 3;
  const int wg  = (o & 7) * cpx + (o >> 3);   // bijective XCD swizzle (grid % 8 == 0)
  const int qtile = wg & 127;
  const int ts    = wg >> 7;
  const int n  = qtile >> 5;
  const int q0 = (qtile & 31) * 128;

  const int tid  = threadIdx.x;
  const int lane = tid & 63;
  const int w    = tid >> 6;   // 0..3 : q-group (32 q each)
  const int l15  = lane & 15;
  const int lg   = lane >> 4;

  const int range = 4096 / TS;
  const int NT    = range >> 5;
  const int tbase = ts * range;

  const unsigned short* kbase = Kb + ((size_t)n * 4096) * 256;
  const unsigned short* vbase = Vt + ((size_t)n * 256) * 4096;

  // per-lane staging offsets (elements)
  unsigned kOff[4], vOff[4];
  #pragma unroll
  for (int ld = 0; ld < 4; ++ld) {
    const int gi  = ld * 256 + w * 64 + lane;        // 16B units
    const int key = gi >> 5, slot = gi & 31;
    kOff[ld] = (unsigned)(key * 256 + (slot ^ (key & 7)) * 8);
    const int d = gi >> 2, gv = gi & 3;
    vOff[ld] = (unsigned)(d * 4096 + ((gv ^ ((d >> 1) & 3)) * 8));
  }

  #define STAGE(BUF, T0)                                                              \
    do {                                                                              \
      unsigned short* kd = &smem[(BUF) * 8192];                                       \
      unsigned short* vd = &smem[16384 + (BUF) * 8192];                               \
      _Pragma("unroll")                                                               \
      for (int ld = 0; ld < 4; ++ld)                                                  \
        __builtin_amdgcn_global_load_lds(                                             \
            (const __attribute__((address_space(1))) unsigned int*)                   \
                (kbase + (size_t)(T0) * 256 + kOff[ld]),                              \
            (__attribute__((address_space(3))) unsigned int*)                         \
                &kd[(ld * 256 + w * 64 + lane) * 8], 16, 0, 0);                       \
      _Pragma("unroll")                                                               \
      for (int ld = 0; ld < 4; ++ld)                                                  \
        __builtin_amdgcn_global_load_lds(                                             \
            (const __attribute__((address_space(1))) unsigned int*)                   \
                (vbase + (size_t)(T0) + vOff[ld]),                                    \
            (__attribute__((address_space(3))) unsigned int*)                         \
                &vd[(ld * 256 + w * 64 + lane) * 8], 16, 0, 0);                       \
    } while (0)

  // Q fragments (B-operand: col=q=l15): 32 q-rows/wave
  s16x8 aq[2][8];
  #pragma unroll
  for (int qk = 0; qk < 2; ++qk) {
    const size_t qoff = ((size_t)(n * 4096 + q0 + w * 32 + qk * 16 + l15)) * 256 + lg * 8;
    #pragma unroll
    for (int kg = 0; kg < 8; ++kg)
      aq[qk][kg] = *reinterpret_cast<const s16x8*>(&Qb[qoff + kg * 32]);
  }
  __builtin_amdgcn_sched_barrier(0);
  asm volatile("s_waitcnt vmcnt(0)" ::: "memory");
  __builtin_amdgcn_sched_barrier(0);

  f32x4 o_acc[2][16];   // O[q=qk*16+l15][d = dt*16 + lg*4 + j]
  #pragma unroll
  for (int qk = 0; qk < 2; ++qk)
    #pragma unroll
    for (int dt = 0; dt < 16; ++dt) o_acc[qk][dt] = {0.f, 0.f, 0.f, 0.f};
  f32x4 l_acc[2];
  l_acc[0] = {0.f, 0.f, 0.f, 0.f};
  l_acc[1] = {0.f, 0.f, 0.f, 0.f};

  s16x8 ones;
  #pragma unroll
  for (int i = 0; i < 8; ++i) ones[i] = (short)0x3F80;   // bf16 1.0

  const float c  = 0.09016844005f;    // (1/sqrt(256)) * log2(e)
  const float b0 = -8.656170245f;     // -96 * c  (static max 96)

  STAGE(0, tbase);   // 8 loads/wave in flight

  for (int i = 0; i < NT; ++i) {
    const int cur = i & 1;

    __builtin_amdgcn_sched_barrier(0);
    asm volatile("s_waitcnt lgkmcnt(0)" ::: "memory");   // my reads of buf[cur^1] done
    __builtin_amdgcn_sched_barrier(0);
    __builtin_amdgcn_s_barrier();                        // B1
    __builtin_amdgcn_sched_barrier(0);

    if (i + 1 < NT) {
      STAGE(cur ^ 1, tbase + (i + 1) * 32);
      asm volatile("s_waitcnt vmcnt(8)" ::: "memory");   // tile i landed (own 8 drained)
    } else {
      asm volatile("s_waitcnt vmcnt(0)" ::: "memory");
    }
    __builtin_amdgcn_sched_barrier(0);
    __builtin_amdgcn_s_barrier();                        // B2
    __builtin_amdgcn_sched_barrier(0);

    const unsigned short* Kt = &smem[cur * 8192];
    const unsigned short* Vw = &smem[16384 + cur * 8192];

    // swapped QK^T: S^T[key][q] = mfma(A=K, B=Q)
    f32x4 s[2][2];
    #pragma unroll
    for (int qk = 0; qk < 2; ++qk) { s[qk][0] = {0.f,0.f,0.f,0.f}; s[qk][1] = {0.f,0.f,0.f,0.f}; }
    __builtin_amdgcn_s_setprio(1);
    #pragma unroll
    for (int nt = 0; nt < 2; ++nt) {
      const int key = nt * 16 + l15;
      #pragma unroll
      for (int kg = 0; kg < 8; ++kg) {
        const s16x8 kf = *reinterpret_cast<const s16x8*>(
            &Kt[key * 256 + (((kg * 4 + lg) ^ (l15 & 7)) * 8)]);
        s[0][nt] = __builtin_amdgcn_mfma_f32_16x16x32_bf16(kf, aq[0][kg], s[0][nt], 0, 0, 0);
        s[1][nt] = __builtin_amdgcn_mfma_f32_16x16x32_bf16(kf, aq[1][kg], s[1][nt], 0, 0, 0);
      }
    }
    __builtin_amdgcn_s_setprio(0);

    // static-max softmax + pack to PV B-frag, all in-register.
    // s[qk][nt][j] = P[key = nt*16 + lg*4 + j][q = qk*16 + l15]
    // pb slot order [nt0 j0..3, nt1 j0..3] == kappa(lg*8+i) mapping.
    s16x8 pb[2];
    #pragma unroll
    for (int qk = 0; qk < 2; ++qk) {
      unsigned u[4];
      #pragma unroll
      for (int h = 0; h < 4; ++h) {
        const int nt = h >> 1, j0 = (h & 1) * 2;
        const float p0 = exp2f(fmaf(s[qk][nt][j0],     c, b0));
        const float p1 = exp2f(fmaf(s[qk][nt][j0 + 1], c, b0));
        asm("v_cvt_pk_bf16_f32 %0, %1, %2" : "=v"(u[h]) : "v"(p0), "v"(p1));
      }
      union { s16x8 v; unsigned uu[4]; } cvt;
      cvt.uu[0] = u[0]; cvt.uu[1] = u[1]; cvt.uu[2] = u[2]; cvt.uu[3] = u[3];
      pb[qk] = cvt.v;
    }

    // PV: O accum. A = V-frag (row=d, k=ks), B = pb (col=q, k=ks).
    __builtin_amdgcn_s_setprio(1);
    l_acc[0] = __builtin_amdgcn_mfma_f32_16x16x32_bf16(ones, pb[0], l_acc[0], 0, 0, 0);
    l_acc[1] = __builtin_amdgcn_mfma_f32_16x16x32_bf16(ones, pb[1], l_acc[1], 0, 0, 0);
    #pragma unroll
    for (int dt = 0; dt < 16; ++dt) {
      const int d = dt * 16 + l15;
      const s16x8 vf = *reinterpret_cast<const s16x8*>(
          &Vw[d * 32 + ((lg ^ ((d >> 1) & 3)) * 8)]);
      o_acc[0][dt] = __builtin_amdgcn_mfma_f32_16x16x32_bf16(vf, pb[0], o_acc[0][dt], 0, 0, 0);
      o_acc[1][dt] = __builtin_amdgcn_mfma_f32_16x16x32_bf16(vf, pb[1], o_acc[1][dt], 0, 0, 0);
    }
    __builtin_amdgcn_s_setprio(0);
  }

  // epilogue: bf16 partials (8B stores); l from ones-MFMA (rows identical)
  #pragma unroll
  for (int qk = 0; qk < 2; ++qk) {
    const size_t r = (size_t)ts * 16384 + n * 4096 + q0 + w * 32 + qk * 16 + l15;
    if (lg == 0) pML[r] = l_acc[qk][0];
    #pragma unroll
    for (int dt = 0; dt < 16; ++dt)
      *reinterpret_cast<s16x4*>(&pO[r * 256 + dt * 16 + lg * 4]) = cvt4(o_acc[qk][dt]);
  }
  #undef STAGE
}

// ---------------- cross-block T-split merge (bf16 partials, plain sums) ----------------
__global__ __launch_bounds__(256) void merge_kernel(
    const unsigned short* __restrict__ pO, const float* __restrict__ pML,
    float* __restrict__ out, const int TS)
{
  const int idx = blockIdx.x * 256 + threadIdx.x;
  const int row = idx >> 6;
  const int dp  = (idx & 63) << 2;

  f32x4 num = {0.f, 0.f, 0.f, 0.f};
  float den = 0.f;
  for (int t = 0; t < TS; ++t) {
    den += pML[(size_t)t * 16384 + row];
    const s16x4 o = *reinterpret_cast<const s16x4*>(&pO[((size_t)t * 16384 + row) * 256 + dp]);
    num[0] += bf2f((unsigned short)o[0]);
    num[1] += bf2f((unsigned short)o[1]);
    num[2] += bf2f((unsigned short)o[2]);
    num[3] += bf2f((unsigned short)o[3]);
  }
  const float inv = 1.0f / den;
  f32x4 y = { num[0] * inv, num[1] * inv, num[2] * inv, num[3] * inv };
  *reinterpret_cast<f32x4*>(&out[(size_t)row * 256 + dp]) = y;
}

extern "C" void kernel_launch(void* const* d_in, const int* in_sizes, int n_in,
                              void* d_out, int out_size, void* d_ws, size_t ws_size,
                              hipStream_t stream) {
  const float* query = (const float*)d_in[0];
  const float* key   = (const float*)d_in[1];
  const float* value = (const float*)d_in[2];
  const float* Wq    = (const float*)d_in[3];
  const float* bq    = (const float*)d_in[4];
  const float* Wk    = (const float*)d_in[5];
  const float* bk    = (const float*)d_in[6];
  const float* Wv    = (const float*)d_in[7];
  const float* bv    = (const float*)d_in[8];
  float* out = (float*)d_out;

  unsigned short* qb = (unsigned short*)d_ws;              // [16384][256] bf16
  unsigned short* kb = qb + (size_t)16384 * 256;           // [16384][256] bf16
  unsigned short* vt = kb + (size_t)16384 * 256;           // [4][256][4096] bf16 (rho-permuted)
  const size_t base    = (size_t)3 * 16384 * 256 * 2;      // 24 MB
  const size_t poBytes = (size_t)16384 * 256 * 2;          // 8 MB per ts (bf16)
  const size_t mlBytes = (size_t)16384 * 4;                // 64 KB per ts
  const int TS = (ws_size >= base + 4 * (poBytes + mlBytes)) ? 4 : 2;
  unsigned short* pO = (unsigned short*)((char*)d_ws + base);
  float* pML = (float*)((char*)d_ws + base + (size_t)TS * poBytes);
  (void)in_sizes; (void)n_in; (void)out_size;

  proj_kernel<<<dim3(128, 2, 3), 256, 0, stream>>>(query, key, value,
                                                   Wq, bq, Wk, bk, Wv, bv,
                                                   qb, kb, vt);
  attn_kernel<<<dim3(128 * TS), 256, 0, stream>>>(qb, kb, vt, pO, pML, TS);
  merge_kernel<<<dim3(4096), 256, 0, stream>>>(pO, pML, out, TS);
}

// Round 21
// 116.457 us; speedup vs baseline: 1.1507x; 1.0060x over previous
//
#include <hip/hip_runtime.h>
#include <hip/hip_bf16.h>

typedef __attribute__((ext_vector_type(4))) float f32x4;
typedef __attribute__((ext_vector_type(8))) short s16x8;
typedef __attribute__((ext_vector_type(4))) short s16x4;

#define DEV __device__ __forceinline__

DEV unsigned short f2bf(float f) {
  union { float f; unsigned u; } v; v.f = f;
  unsigned r = v.u + 0x7FFFu + ((v.u >> 16) & 1u);
  return (unsigned short)(r >> 16);
}

DEV s16x4 cvt4(const f32x4 a) {
  unsigned u0, u1;
  asm("v_cvt_pk_bf16_f32 %0, %1, %2" : "=v"(u0) : "v"(a[0]), "v"(a[1]));
  asm("v_cvt_pk_bf16_f32 %0, %1, %2" : "=v"(u1) : "v"(a[2]), "v"(a[3]));
  union { s16x4 v; unsigned uu[2]; } r;
  r.uu[0] = u0; r.uu[1] = u1;
  return r.v;
}

DEV float bf2f(unsigned short h) {
  union { unsigned u; float f; } v;
  v.u = ((unsigned)h) << 16;
  return v.f;
}

// ---------------- fused QKV projection (R17 exact — best measured) ----------------
// out_mode 1 (V): writes V^T[n][d][t'] with t' rho-permuted within each 32-key
// block: ks(t) = ((t>>2)&3)*8 + ((t>>4)&1)*4 + (t&3). Permutation spans 64B.
__global__ __launch_bounds__(256) void proj_kernel(
    const float* __restrict__ Qx, const float* __restrict__ Kx, const float* __restrict__ Vx,
    const float* __restrict__ Wq, const float* __restrict__ bq,
    const float* __restrict__ Wk, const float* __restrict__ bk,
    const float* __restrict__ Wv, const float* __restrict__ bv,
    unsigned short* __restrict__ qb, unsigned short* __restrict__ kb,
    unsigned short* __restrict__ vt)
{
  const int z = blockIdx.z;
  const float* X = (z == 0) ? Qx : (z == 1) ? Kx : Vx;
  const float* W = (z == 0) ? Wq : (z == 1) ? Wk : Wv;
  const float* B = (z == 0) ? bq : (z == 1) ? bk : bv;
  unsigned short* Y = (z == 0) ? qb : (z == 1) ? kb : vt;
  const int out_mode = (z == 2);

  const int row0 = blockIdx.x * 128;
  const int col0 = blockIdx.y * 128;
  const int tid  = threadIdx.x;
  const int lane = tid & 63;
  const int w    = tid >> 6;
  const int wr = w >> 1, wc = w & 1;
  const int l15 = lane & 15, lg = lane >> 4;

  __shared__ unsigned short As[128][40];
  __shared__ unsigned short Bs[128][40];

  f32x4 acc[4][4];
  #pragma unroll
  for (int i = 0; i < 4; ++i)
    #pragma unroll
    for (int j = 0; j < 4; ++j) acc[i][j] = {0.f, 0.f, 0.f, 0.f};

  const int lr = tid >> 3;
  const int lc = (tid & 7) << 2;

  for (int k0 = 0; k0 < 256; k0 += 32) {
    __syncthreads();
    #pragma unroll
    for (int p = 0; p < 4; ++p) {
      const int r = p * 32 + lr;
      f32x4 a = *reinterpret_cast<const f32x4*>(&X[(size_t)(row0 + r) * 256 + k0 + lc]);
      *reinterpret_cast<s16x4*>(&As[r][lc]) = cvt4(a);
      f32x4 b = *reinterpret_cast<const f32x4*>(&W[(size_t)(col0 + r) * 256 + k0 + lc]);
      *reinterpret_cast<s16x4*>(&Bs[r][lc]) = cvt4(b);
    }
    __syncthreads();
    s16x8 af[4], bf[4];
    #pragma unroll
    for (int mi = 0; mi < 4; ++mi)
      af[mi] = *reinterpret_cast<const s16x8*>(&As[wr * 64 + mi * 16 + l15][lg * 8]);
    #pragma unroll
    for (int ni = 0; ni < 4; ++ni)
      bf[ni] = *reinterpret_cast<const s16x8*>(&Bs[wc * 64 + ni * 16 + l15][lg * 8]);
    #pragma unroll
    for (int mi = 0; mi < 4; ++mi)
      #pragma unroll
      for (int ni = 0; ni < 4; ++ni)
        acc[mi][ni] = __builtin_amdgcn_mfma_f32_16x16x32_bf16(af[mi], bf[ni], acc[mi][ni], 0, 0, 0);
  }

  #pragma unroll
  for (int ni = 0; ni < 4; ++ni) {
    const int col = col0 + wc * 64 + ni * 16 + l15;
    const float bv_ = B[col];
    #pragma unroll
    for (int mi = 0; mi < 4; ++mi)
      #pragma unroll
      for (int j = 0; j < 4; ++j) {
        const int row = row0 + wr * 64 + mi * 16 + lg * 4 + j;
        const unsigned short h = f2bf(acc[mi][ni][j] + bv_);
        if (out_mode == 0) {
          Y[(size_t)row * 256 + col] = h;
        } else {
          const int t  = row & 4095;
          const int tp = (t & ~31) | (((t >> 2) & 3) * 8 + ((t >> 4) & 1) * 4 + (t & 3));
          Y[((size_t)((row >> 12) * 256 + col)) * 4096 + tp] = h;
        }
      }
  }
}

// ---------------- flash attention, swapped-QK in-register P (R12 structure, verified) -------
// 256 thr = 4 waves x 32q (q-span 128). One shared 32-key K/V tile, dbuf,
// 2 barriers/iter, counted vmcnt(8). S^T = mfma(K,Q) -> P lane-local;
// static-max softmax; in-register P pack; ones-MFMA row-sum.
// Prologue: Q loads then STAGE(0) then vmcnt(8) (drains Q, keeps staging in flight).
// Keys split across blocks (TS=4); bf16 unnormalized partials to ws.
__global__ __launch_bounds__(256, 2) void attn_kernel(
    const unsigned short* __restrict__ Qb,
    const unsigned short* __restrict__ Kb,
    const unsigned short* __restrict__ Vt,
    unsigned short* __restrict__ pO, float* __restrict__ pML, const int TS)
{
  // K tile [32key][256d] 16KB x2; granule slot g holds global granule g^(key&7)
  // V tile [256d][32ks]  16KB x2; granule slot g holds global granule g^((d>>1)&3)
  __shared__ __align__(16) unsigned short smem[32768];   // 32K K + 32K V = 64KB

  const int o   = blockIdx.x;
  const int cpx = gridDim.x >> 3;
  const int wg  = (o & 7) * cpx + (o >> 3);   // bijective XCD swizzle (grid % 8 == 0)
  const int qtile = wg & 127;
  const int ts    = wg >> 7;
  const int n  = qtile >> 5;
  const int q0 = (qtile & 31) * 128;

  const int tid  = threadIdx.x;
  const int lane = tid & 63;
  const int w    = tid >> 6;   // 0..3 : q-group (32 q each)
  const int l15  = lane & 15;
  const int lg   = lane >> 4;

  const int range = 4096 / TS;
  const int NT    = range >> 5;
  const int tbase = ts * range;

  const unsigned short* kbase = Kb + ((size_t)n * 4096) * 256;
  const unsigned short* vbase = Vt + ((size_t)n * 256) * 4096;

  // per-lane staging offsets (elements)
  unsigned kOff[4], vOff[4];
  #pragma unroll
  for (int ld = 0; ld < 4; ++ld) {
    const int gi  = ld * 256 + w * 64 + lane;        // 16B units
    const int key = gi >> 5, slot = gi & 31;
    kOff[ld] = (unsigned)(key * 256 + (slot ^ (key & 7)) * 8);
    const int d = gi >> 2, gv = gi & 3;
    vOff[ld] = (unsigned)(d * 4096 + ((gv ^ ((d >> 1) & 3)) * 8));
  }

  #define STAGE(BUF, T0)                                                              \
    do {                                                                              \
      unsigned short* kd = &smem[(BUF) * 8192];                                       \
      unsigned short* vd = &smem[16384 + (BUF) * 8192];                               \
      _Pragma("unroll")                                                               \
      for (int ld = 0; ld < 4; ++ld)                                                  \
        __builtin_amdgcn_global_load_lds(                                             \
            (const __attribute__((address_space(1))) unsigned int*)                   \
                (kbase + (size_t)(T0) * 256 + kOff[ld]),                              \
            (__attribute__((address_space(3))) unsigned int*)                         \
                &kd[(ld * 256 + w * 64 + lane) * 8], 16, 0, 0);                       \
      _Pragma("unroll")                                                               \
      for (int ld = 0; ld < 4; ++ld)                                                  \
        __builtin_amdgcn_global_load_lds(                                             \
            (const __attribute__((address_space(1))) unsigned int*)                   \
                (vbase + (size_t)(T0) + vOff[ld]),                                    \
            (__attribute__((address_space(3))) unsigned int*)                         \
                &vd[(ld * 256 + w * 64 + lane) * 8], 16, 0, 0);                       \
    } while (0)

  // Q fragments (B-operand: col=q=l15): 32 q-rows/wave
  s16x8 aq[2][8];
  #pragma unroll
  for (int qk = 0; qk < 2; ++qk) {
    const size_t qoff = ((size_t)(n * 4096 + q0 + w * 32 + qk * 16 + l15)) * 256 + lg * 8;
    #pragma unroll
    for (int kg = 0; kg < 8; ++kg)
      aq[qk][kg] = *reinterpret_cast<const s16x8*>(&Qb[qoff + kg * 32]);
  }
  __builtin_amdgcn_sched_barrier(0);
  STAGE(0, tbase);                                     // K(0)/V(0): 8 loads, newest
  __builtin_amdgcn_sched_barrier(0);
  asm volatile("s_waitcnt vmcnt(8)" ::: "memory");     // drain Q loads; staging stays in flight
  __builtin_amdgcn_sched_barrier(0);

  f32x4 o_acc[2][16];   // O[q=qk*16+l15][d = dt*16 + lg*4 + j]
  #pragma unroll
  for (int qk = 0; qk < 2; ++qk)
    #pragma unroll
    for (int dt = 0; dt < 16; ++dt) o_acc[qk][dt] = {0.f, 0.f, 0.f, 0.f};
  f32x4 l_acc[2];
  l_acc[0] = {0.f, 0.f, 0.f, 0.f};
  l_acc[1] = {0.f, 0.f, 0.f, 0.f};

  s16x8 ones;
  #pragma unroll
  for (int i = 0; i < 8; ++i) ones[i] = (short)0x3F80;   // bf16 1.0

  const float c  = 0.09016844005f;    // (1/sqrt(256)) * log2(e)
  const float b0 = -8.656170245f;     // -96 * c  (static max 96)

  for (int i = 0; i < NT; ++i) {
    const int cur = i & 1;

    __builtin_amdgcn_sched_barrier(0);
    asm volatile("s_waitcnt lgkmcnt(0)" ::: "memory");   // my reads of buf[cur^1] done
    __builtin_amdgcn_sched_barrier(0);
    __builtin_amdgcn_s_barrier();                        // B1
    __builtin_amdgcn_sched_barrier(0);

    if (i + 1 < NT) {
      STAGE(cur ^ 1, tbase + (i + 1) * 32);
      asm volatile("s_waitcnt vmcnt(8)" ::: "memory");   // tile i landed (own 8 drained)
    } else {
      asm volatile("s_waitcnt vmcnt(0)" ::: "memory");
    }
    __builtin_amdgcn_sched_barrier(0);
    __builtin_amdgcn_s_barrier();                        // B2
    __builtin_amdgcn_sched_barrier(0);

    const unsigned short* Kt = &smem[cur * 8192];
    const unsigned short* Vw = &smem[16384 + cur * 8192];

    // swapped QK^T: S^T[key][q] = mfma(A=K, B=Q)
    f32x4 s[2][2];
    #pragma unroll
    for (int qk = 0; qk < 2; ++qk) { s[qk][0] = {0.f,0.f,0.f,0.f}; s[qk][1] = {0.f,0.f,0.f,0.f}; }
    __builtin_amdgcn_s_setprio(1);
    #pragma unroll
    for (int nt = 0; nt < 2; ++nt) {
      const int key = nt * 16 + l15;
      #pragma unroll
      for (int kg = 0; kg < 8; ++kg) {
        const s16x8 kf = *reinterpret_cast<const s16x8*>(
            &Kt[key * 256 + (((kg * 4 + lg) ^ (l15 & 7)) * 8)]);
        s[0][nt] = __builtin_amdgcn_mfma_f32_16x16x32_bf16(kf, aq[0][kg], s[0][nt], 0, 0, 0);
        s[1][nt] = __builtin_amdgcn_mfma_f32_16x16x32_bf16(kf, aq[1][kg], s[1][nt], 0, 0, 0);
      }
    }
    __builtin_amdgcn_s_setprio(0);

    // static-max softmax + pack to PV B-frag, all in-register.
    // s[qk][nt][j] = P[key = nt*16 + lg*4 + j][q = qk*16 + l15]
    // pb slot order [nt0 j0..3, nt1 j0..3] == kappa(lg*8+i) mapping.
    s16x8 pb[2];
    #pragma unroll
    for (int qk = 0; qk < 2; ++qk) {
      unsigned u[4];
      #pragma unroll
      for (int h = 0; h < 4; ++h) {
        const int nt = h >> 1, j0 = (h & 1) * 2;
        const float p0 = exp2f(fmaf(s[qk][nt][j0],     c, b0));
        const float p1 = exp2f(fmaf(s[qk][nt][j0 + 1], c, b0));
        asm("v_cvt_pk_bf16_f32 %0, %1, %2" : "=v"(u[h]) : "v"(p0), "v"(p1));
      }
      union { s16x8 v; unsigned uu[4]; } cvt;
      cvt.uu[0] = u[0]; cvt.uu[1] = u[1]; cvt.uu[2] = u[2]; cvt.uu[3] = u[3];
      pb[qk] = cvt.v;
    }

    // PV: O accum. A = V-frag (row=d, k=ks), B = pb (col=q, k=ks).
    __builtin_amdgcn_s_setprio(1);
    l_acc[0] = __builtin_amdgcn_mfma_f32_16x16x32_bf16(ones, pb[0], l_acc[0], 0, 0, 0);
    l_acc[1] = __builtin_amdgcn_mfma_f32_16x16x32_bf16(ones, pb[1], l_acc[1], 0, 0, 0);
    #pragma unroll
    for (int dt = 0; dt < 16; ++dt) {
      const int d = dt * 16 + l15;
      const s16x8 vf = *reinterpret_cast<const s16x8*>(
          &Vw[d * 32 + ((lg ^ ((d >> 1) & 3)) * 8)]);
      o_acc[0][dt] = __builtin_amdgcn_mfma_f32_16x16x32_bf16(vf, pb[0], o_acc[0][dt], 0, 0, 0);
      o_acc[1][dt] = __builtin_amdgcn_mfma_f32_16x16x32_bf16(vf, pb[1], o_acc[1][dt], 0, 0, 0);
    }
    __builtin_amdgcn_s_setprio(0);
  }

  // epilogue: bf16 partials (8B stores); l from ones-MFMA (rows identical)
  #pragma unroll
  for (int qk = 0; qk < 2; ++qk) {
    const size_t r = (size_t)ts * 16384 + n * 4096 + q0 + w * 32 + qk * 16 + l15;
    if (lg == 0) pML[r] = l_acc[qk][0];
    #pragma unroll
    for (int dt = 0; dt < 16; ++dt)
      *reinterpret_cast<s16x4*>(&pO[r * 256 + dt * 16 + lg * 4]) = cvt4(o_acc[qk][dt]);
  }
  #undef STAGE
}

// ---------------- cross-block T-split merge (bf16 partials, plain sums) ----------------
__global__ __launch_bounds__(256) void merge_kernel(
    const unsigned short* __restrict__ pO, const float* __restrict__ pML,
    float* __restrict__ out, const int TS)
{
  const int idx = blockIdx.x * 256 + threadIdx.x;
  const int row = idx >> 6;
  const int dp  = (idx & 63) << 2;

  f32x4 num = {0.f, 0.f, 0.f, 0.f};
  float den = 0.f;
  for (int t = 0; t < TS; ++t) {
    den += pML[(size_t)t * 16384 + row];
    const s16x4 o = *reinterpret_cast<const s16x4*>(&pO[((size_t)t * 16384 + row) * 256 + dp]);
    num[0] += bf2f((unsigned short)o[0]);
    num[1] += bf2f((unsigned short)o[1]);
    num[2] += bf2f((unsigned short)o[2]);
    num[3] += bf2f((unsigned short)o[3]);
  }
  const float inv = 1.0f / den;
  f32x4 y = { num[0] * inv, num[1] * inv, num[2] * inv, num[3] * inv };
  *reinterpret_cast<f32x4*>(&out[(size_t)row * 256 + dp]) = y;
}

extern "C" void kernel_launch(void* const* d_in, const int* in_sizes, int n_in,
                              void* d_out, int out_size, void* d_ws, size_t ws_size,
                              hipStream_t stream) {
  const float* query = (const float*)d_in[0];
  const float* key   = (const float*)d_in[1];
  const float* value = (const float*)d_in[2];
  const float* Wq    = (const float*)d_in[3];
  const float* bq    = (const float*)d_in[4];
  const float* Wk    = (const float*)d_in[5];
  const float* bk    = (const float*)d_in[6];
  const float* Wv    = (const float*)d_in[7];
  const float* bv    = (const float*)d_in[8];
  float* out = (float*)d_out;

  unsigned short* qb = (unsigned short*)d_ws;              // [16384][256] bf16
  unsigned short* kb = qb + (size_t)16384 * 256;           // [16384][256] bf16
  unsigned short* vt = kb + (size_t)16384 * 256;           // [4][256][4096] bf16 (rho-permuted)
  const size_t base    = (size_t)3 * 16384 * 256 * 2;      // 24 MB
  const size_t poBytes = (size_t)16384 * 256 * 2;          // 8 MB per ts (bf16)
  const size_t mlBytes = (size_t)16384 * 4;                // 64 KB per ts
  const int TS = (ws_size >= base + 4 * (poBytes + mlBytes)) ? 4 : 2;
  unsigned short* pO = (unsigned short*)((char*)d_ws + base);
  float* pML = (float*)((char*)d_ws + base + (size_t)TS * poBytes);
  (void)in_sizes; (void)n_in; (void)out_size;

  proj_kernel<<<dim3(128, 2, 3), 256, 0, stream>>>(query, key, value,
                                                   Wq, bq, Wk, bk, Wv, bv,
                                                   qb, kb, vt);
  attn_kernel<<<dim3(128 * TS), 256, 0, stream>>>(qb, kb, vt, pO, pML, TS);
  merge_kernel<<<dim3(4096), 256, 0, stream>>>(pO, pML, out, TS);
}